// Round 2
// baseline (9.676 us; speedup 1.0000x reference)
//
#include <hip/hip_runtime.h>
#include <math.h>

// Reference collapses analytically:
//   - Initial |0...0> + per-wire single-qubit gates => product state.
//   - CNOT(0,1) commutes with Z_0; CNOT(i,i+1) for i>=1 don't touch qubit 0
//     => <Z_0> unchanged by the entangling layer.
//   - <Z> of RY(b)RX(a)|0> = cos(a)*cos(b).
// => out[b] = sigmoid( cos(params[0]) * cos( dot(x[b,:], W[0,:]) ) )

#define BATCH 4096
#define FEAT  256

__global__ __launch_bounds__(256) void gate_circuit_collapsed(
    const float* __restrict__ x,      // [BATCH, FEAT]
    const float* __restrict__ W,      // [14, FEAT] (only row 0 used)
    const float* __restrict__ params, // [14] (only params[0] used)
    float* __restrict__ out)          // [BATCH]
{
    const int tid  = threadIdx.x;
    const int lane = tid & 63;          // wavefront = 64
    const int sub  = lane & 15;         // 16 lanes cooperate on one row
    const int r    = lane >> 4;         // 4 rows per wave
    const int wave = tid >> 6;          // 4 waves per block
    const int row  = blockIdx.x * 16 + wave * 4 + r;  // 16 rows per block

    const float4* __restrict__ xrow = reinterpret_cast<const float4*>(x + (size_t)row * FEAT);
    const float4* __restrict__ wrow = reinterpret_cast<const float4*>(W);

    // 16 lanes x 4 float4 = 256 floats = one row. 8 independent loads/lane.
    float dot = 0.0f;
    #pragma unroll
    for (int j = 0; j < 4; ++j) {
        const float4 xv = xrow[sub + j * 16];
        const float4 wv = wrow[sub + j * 16];
        dot += xv.x * wv.x + xv.y * wv.y + xv.z * wv.z + xv.w * wv.w;
    }

    // 16-lane butterfly reduction (4 steps instead of 6)
    #pragma unroll
    for (int off = 8; off >= 1; off >>= 1)
        dot += __shfl_xor(dot, off, 64);

    if (sub == 0) {
        const float z = cosf(params[0]) * cosf(dot);
        out[row] = 1.0f / (1.0f + expf(-z)); // sigmoid
    }
}

extern "C" void kernel_launch(void* const* d_in, const int* in_sizes, int n_in,
                              void* d_out, int out_size, void* d_ws, size_t ws_size,
                              hipStream_t stream) {
    const float* x = (const float*)d_in[0];
    const float* W = (const float*)d_in[1];
    const float* p = (const float*)d_in[2];
    float* out     = (float*)d_out;

    gate_circuit_collapsed<<<dim3(BATCH / 16), dim3(256), 0, stream>>>(x, W, p, out);
}